// Round 1
// baseline (159.860 us; speedup 1.0000x reference)
//
#include <hip/hip_runtime.h>

// TokenSelector: out[b,h,q,s,:] = kv[b,h,indices[b,h,q,s],:]
// Shapes: kv (2,16,4096,128) f32, indices (2,16,512,64) int, out (2,16,512,64,128) f32.
// Pure gather, memory-bound (512 MiB output writes dominate).

namespace {
constexpr long long B = 2;
constexpr long long H = 16;
constexpr long long T_KV = 4096;
constexpr long long D = 128;
constexpr long long T_Q = 512;
constexpr long long N_SEL = 64;

constexpr long long N_ROWS = B * H * T_Q * N_SEL;       // 1,048,576 gathered rows
constexpr long long VEC_PER_ROW = D / 4;                // 32 float4 per row
constexpr long long TOTAL_VEC = N_ROWS * VEC_PER_ROW;   // 33,554,432 float4
constexpr long long ROWS_PER_BH = T_Q * N_SEL;          // 32768

__global__ void token_selector_gather(const float4* __restrict__ kv,
                                      const int* __restrict__ idx,
                                      float4* __restrict__ out) {
    long long t = (long long)blockIdx.x * blockDim.x + threadIdx.x;
    const long long stride = (long long)gridDim.x * blockDim.x;
    for (; t < TOTAL_VEC; t += stride) {
        const long long row = t >> 5;         // / VEC_PER_ROW
        const int lane = (int)(t & 31);       // float4 slot within the row
        const long long bh = row >> 15;       // / ROWS_PER_BH
        const int r = idx[row];               // gathered kv row (same addr across 32 lanes)
        const float4* src = kv + ((bh * T_KV + (long long)r) << 5);
        out[t] = src[lane];
    }
}
} // namespace

extern "C" void kernel_launch(void* const* d_in, const int* in_sizes, int n_in,
                              void* d_out, int out_size, void* d_ws, size_t ws_size,
                              hipStream_t stream) {
    const float4* kv = (const float4*)d_in[0];
    const int* idx = (const int*)d_in[1];
    float4* out = (float4*)d_out;

    const int block = 256;
    const int grid = 2048;  // 256 CU x 8 blocks, grid-stride covers the rest
    token_selector_gather<<<grid, block, 0, stream>>>(kv, idx, out);
}